// Round 5
// baseline (175.128 us; speedup 1.0000x reference)
//
#include <hip/hip_runtime.h>

// Lorenz RK4, B=16384, NT=2000, dt=0.01. out[b*6003 + d*2001 + t].
//
// Round-5: ALIGN the output tiles. Offsets within a row are 1+t; round-4
// tiles started at t=64k -> byte offset 4 mod 256 -> every 256B store chunk
// had partial head/tail cache lines (ECC RMW, 13% write amplification,
// ~2.3 TB/s wall). Retile: tile0 = 63 steps (offsets 1..63), tiles 1..30
// start at offset 64k (256B-aligned), tail = 17 (offsets 1984..2000).
// Everything else identical to round 4 (isolate one variable).

#define TROWS  2001
#define ROWS   64          // trajectories per block
#define LROWS  65          // pad -> <=2-way LDS banking
#define TT     64

#define FMA(a,b,c) __builtin_fmaf((a),(b),(c))

__global__ __launch_bounds__(192) void lorenz_rk4(
    const float* __restrict__ x0,
    const float* __restrict__ p,
    float* __restrict__ out)
{
#pragma clang fp contract(off)
    __shared__ float buf[2][3][TT][LROWS];   // 99.8 KB

    const int tid  = threadIdx.x;
    const int lane = tid & 63;
    const int b0   = blockIdx.x * ROWS;

    if (tid < 64) {
        // ================= compute wave =================
        const float p0  = p[0], p1 = p[1], p2n = -p[2];
        const float h1 = 0.01f;
        const float h2 = 0.01f / 2.0f;
        const float h6 = 0.01f / 6.0f;
        const int b = b0 + lane;
        float x = x0[3*b + 0], y = x0[3*b + 1], z = x0[3*b + 2];

        {   // t = 0 column (once, scattered dwords, negligible)
            size_t g = (size_t)b * (3 * TROWS);
            out[g] = x; out[g + TROWS] = y; out[g + 2*TROWS] = z;
        }

#define STEP() do {                                                          \
        float k1x = p0 * (y - x);                                            \
        float k1y = FMA(x, p1 - z, -y);                                      \
        float k1z = FMA(p2n, z, x * y);                                      \
        float ax = FMA(h2,k1x,x), ay = FMA(h2,k1y,y), az = FMA(h2,k1z,z);    \
        float k2x = p0 * (ay - ax);                                          \
        float k2y = FMA(ax, p1 - az, -ay);                                   \
        float k2z = FMA(p2n, az, ax * ay);                                   \
        float bx = FMA(h2,k2x,x), by = FMA(h2,k2y,y), bz = FMA(h2,k2z,z);    \
        float k3x = p0 * (by - bx);                                          \
        float k3y = FMA(bx, p1 - bz, -by);                                   \
        float k3z = FMA(p2n, bz, bx * by);                                   \
        float cx = FMA(h1,k3x,x), cy = FMA(h1,k3y,y), cz = FMA(h1,k3z,z);    \
        float k4x = p0 * (cy - cx);                                          \
        float k4y = FMA(cx, p1 - cz, -cy);                                   \
        float k4z = FMA(p2n, cz, cx * cy);                                   \
        float sx = FMA(2.0f,k2x,k1x); sx = FMA(2.0f,k3x,sx); sx += k4x;      \
        float sy = FMA(2.0f,k2y,k1y); sy = FMA(2.0f,k3y,sy); sy += k4y;      \
        float sz = FMA(2.0f,k2z,k1z); sz = FMA(2.0f,k3z,sz); sz += k4z;      \
        x = FMA(h6,sx,x); y = FMA(h6,sy,y); z = FMA(h6,sz,z);                \
    } while (0)

        // tile 0: 63 steps -> buf 0 (output offsets 1..63)
#pragma unroll 7
        for (int tl = 0; tl < 63; ++tl) {
            STEP();
            buf[0][0][tl][lane] = x;
            buf[0][1][tl][lane] = y;
            buf[0][2][tl][lane] = z;
        }
        __syncthreads();                      // tile 0 ready

        // tiles 1..30: 64 steps each, output offsets 64k..64k+63 (aligned)
        for (int k = 1; k <= 30; ++k) {
            float* bb = &buf[k & 1][0][0][0];
#pragma unroll 8
            for (int tl = 0; tl < TT; ++tl) {
                STEP();
                bb[              tl*LROWS + lane] = x;
                bb[  TT*LROWS  + tl*LROWS + lane] = y;
                bb[2*TT*LROWS  + tl*LROWS + lane] = z;
            }
            __syncthreads();                  // tile k ready
        }

        // tail: 17 steps -> buf 1 (offsets 1984..2000)
#pragma unroll
        for (int tl = 0; tl < 17; ++tl) {
            STEP();
            buf[1][0][tl][lane] = x;
            buf[1][1][tl][lane] = y;
            buf[1][2][tl][lane] = z;
        }
        __syncthreads();                      // tail ready
#undef STEP
    } else {
        // ================= writer waves =================
        const int w     = (tid >> 6) - 1;     // 0 or 1
        const int rbase = w * 32;             // rows [rbase, rbase+32)
        const int t     = lane;               // time within tile

        // tile 0: 63 values at offsets 1..63
        __syncthreads();
        {
            const float* bb = &buf[0][0][0][0];
            if (t < 63) {
                size_t g = (size_t)(b0 + rbase) * (3 * TROWS) + 1 + t;
#pragma unroll 4
                for (int r = rbase; r < rbase + 32; ++r) {
                    out[g]             = bb[              t*LROWS + r];
                    out[g +     TROWS] = bb[  TT*LROWS  + t*LROWS + r];
                    out[g + 2 * TROWS] = bb[2*TT*LROWS  + t*LROWS + r];
                    g += (size_t)(3 * TROWS);
                }
            }
        }

        // tiles 1..30: aligned 256B chunks at offsets 64k
        for (int k = 1; k <= 30; ++k) {
            __syncthreads();
            const float* bb = &buf[k & 1][0][0][0];
            size_t g = (size_t)(b0 + rbase) * (3 * TROWS) + (size_t)TT * k + t;
#pragma unroll 4
            for (int r = rbase; r < rbase + 32; ++r) {
                out[g]             = bb[              t*LROWS + r];
                out[g +     TROWS] = bb[  TT*LROWS  + t*LROWS + r];
                out[g + 2 * TROWS] = bb[2*TT*LROWS  + t*LROWS + r];
                g += (size_t)(3 * TROWS);
            }
        }

        // tail: 17 values at offsets 1984..2000
        __syncthreads();
        {
            const float* bb = &buf[1][0][0][0];
            if (t < 17) {
                size_t g = (size_t)(b0 + rbase) * (3 * TROWS) + 1984 + t;
#pragma unroll 4
                for (int r = rbase; r < rbase + 32; ++r) {
                    out[g]             = bb[              t*LROWS + r];
                    out[g +     TROWS] = bb[  TT*LROWS  + t*LROWS + r];
                    out[g + 2 * TROWS] = bb[2*TT*LROWS  + t*LROWS + r];
                    g += (size_t)(3 * TROWS);
                }
            }
        }
    }
}

extern "C" void kernel_launch(void* const* d_in, const int* in_sizes, int n_in,
                              void* d_out, int out_size, void* d_ws, size_t ws_size,
                              hipStream_t stream)
{
    const float* x0  = (const float*)d_in[0];
    const float* p   = (const float*)d_in[1];
    float*       out = (float*)d_out;

    const int B = in_sizes[0] / 3;        // 16384
    const int nblocks = B / ROWS;         // 256

    lorenz_rk4<<<nblocks, 192, 0, stream>>>(x0, p, out);
}